// Round 2
// baseline (303.915 us; speedup 1.0000x reference)
//
#include <hip/hip_runtime.h>

typedef unsigned short u16;
typedef short v8s __attribute__((ext_vector_type(8)));   // 8 bf16 in 4 VGPRs (guide-verified)
typedef float f4 __attribute__((ext_vector_type(4)));

#define NROWS 262144

__device__ __forceinline__ u16 f2bf(float f) {
  union { float f; unsigned int i; } x; x.f = f;
  unsigned int r = x.i + 0x7fffu + ((x.i >> 16) & 1u);   // round-nearest-even
  return (u16)(r >> 16);
}

// ---------------------------------------------------------------------------
// Kernel 1: fold M = Wo @ Wv (f32 math -> bf16), c = Wo @ bv + bo (f32),
// copy g/be (f32) into ws. grid 8 x 256 -> 2048 items = mat(2) x n(64) x kg(16)
// ---------------------------------------------------------------------------
__global__ void fuse_weights(const float* __restrict__ Wo1, const float* __restrict__ Wv2,
                             const float* __restrict__ bv2, const float* __restrict__ bo1,
                             const float* __restrict__ Wo2, const float* __restrict__ Wv1,
                             const float* __restrict__ bv1, const float* __restrict__ bo2,
                             const float* __restrict__ g1,  const float* __restrict__ be1,
                             const float* __restrict__ g2,  const float* __restrict__ be2,
                             u16* __restrict__ M1, u16* __restrict__ M2,
                             float* __restrict__ cgb) {
  int item = blockIdx.x * 256 + threadIdx.x;   // 0..2047
  int mat = item >> 10;                        // 0: path1, 1: path2
  int n   = (item >> 4) & 63;                  // output feature (row of M)
  int k0  = (item & 15) * 4;                   // 4 columns per thread
  const float* Wo = mat ? Wo2 : Wo1;
  const float* Wv = mat ? Wv1 : Wv2;
  float a0 = 0.f, a1 = 0.f, a2 = 0.f, a3 = 0.f;
  for (int j = 0; j < 64; ++j) {
    float w = Wo[n * 64 + j];
    a0 += w * Wv[j * 64 + k0 + 0];
    a1 += w * Wv[j * 64 + k0 + 1];
    a2 += w * Wv[j * 64 + k0 + 2];
    a3 += w * Wv[j * 64 + k0 + 3];
  }
  u16* M = mat ? M2 : M1;
  M[n * 64 + k0 + 0] = f2bf(a0);
  M[n * 64 + k0 + 1] = f2bf(a1);
  M[n * 64 + k0 + 2] = f2bf(a2);
  M[n * 64 + k0 + 3] = f2bf(a3);
  if ((item & 15) == 0) {
    const float* bv = mat ? bv1 : bv2;
    const float* bo = mat ? bo2 : bo1;
    float s = bo[n];
    for (int j = 0; j < 64; ++j) s += Wo[n * 64 + j] * bv[j];
    cgb[mat * 64 + n] = s;                       // c1 @0, c2 @64
    const float* g  = mat ? g2 : g1;
    const float* be = mat ? be2 : be1;
    cgb[128 + mat * 128 + n] = g[n];             // g1 @128, g2 @256
    cgb[192 + mat * 128 + n] = be[n];            // be1 @192, be2 @320
  }
}

// ---------------------------------------------------------------------------
// Kernel 2: per 16-row tile, per path: D = M(64x64) @ X^T(64x16) via
// mfma_f32_16x16x32_bf16 (4 M-tiles x 2 K-steps), then +c +residual, LN, store.
// C-layout: lane holds features {mt*16 + quad*4 + reg} of batch row (lane&15).
// ---------------------------------------------------------------------------
__device__ __forceinline__ v8s cvt8(const float* p) {
  f4 xa = *(const f4*)(p);
  f4 xb = *(const f4*)(p + 4);
  v8s b;
  b[0] = (short)f2bf(xa[0]); b[1] = (short)f2bf(xa[1]);
  b[2] = (short)f2bf(xa[2]); b[3] = (short)f2bf(xa[3]);
  b[4] = (short)f2bf(xb[0]); b[5] = (short)f2bf(xb[1]);
  b[6] = (short)f2bf(xb[2]); b[7] = (short)f2bf(xb[3]);
  return b;
}

__device__ __forceinline__ void do_path(
    const float* __restrict__ xsrc,   // matmul input rows (B x 64)
    const float* __restrict__ rsrc,   // residual rows (B x 64)
    const v8s a[4][2],                // weight A-fragments
    const float* __restrict__ cgb, int coff, int goff, int boff,
    float* __restrict__ outp, int r0, int lane) {
  const int quad = lane >> 4;
  const int l15  = lane & 15;
  // B-fragment: B[k = quad*8+j][n = l15] = X[r0+l15][k]
  const float* xrow = xsrc + (size_t)(r0 + l15) * 64;
  v8s b0 = cvt8(xrow + quad * 8);
  v8s b1 = cvt8(xrow + quad * 8 + 32);
  f4 acc[4];
#pragma unroll
  for (int mt = 0; mt < 4; ++mt) {
    f4 c = {0.f, 0.f, 0.f, 0.f};
    c = __builtin_amdgcn_mfma_f32_16x16x32_bf16(a[mt][0], b0, c, 0, 0, 0);
    c = __builtin_amdgcn_mfma_f32_16x16x32_bf16(a[mt][1], b1, c, 0, 0, 0);
    acc[mt] = c;
  }
  const float* rrow = rsrc + (size_t)(r0 + l15) * 64;
  float vals[16];
  float sum = 0.f, sq = 0.f;
#pragma unroll
  for (int mt = 0; mt < 4; ++mt) {
    int fo = mt * 16 + quad * 4;
    f4 rv = *(const f4*)(rrow + fo);
    f4 cf = *(const f4*)(cgb + coff + fo);
    float x0 = acc[mt][0] + cf[0] + rv[0];
    float x1 = acc[mt][1] + cf[1] + rv[1];
    float x2 = acc[mt][2] + cf[2] + rv[2];
    float x3 = acc[mt][3] + cf[3] + rv[3];
    vals[mt * 4 + 0] = x0; vals[mt * 4 + 1] = x1;
    vals[mt * 4 + 2] = x2; vals[mt * 4 + 3] = x3;
    sum += x0 + x1 + x2 + x3;
    sq  += x0 * x0 + x1 * x1 + x2 * x2 + x3 * x3;
  }
  // each batch row is split across lanes {l, l^16, l^32, l^48}: butterfly quads
  sum += __shfl_xor(sum, 16, 64);
  sq  += __shfl_xor(sq,  16, 64);
  sum += __shfl_xor(sum, 32, 64);
  sq  += __shfl_xor(sq,  32, 64);
  float mean = sum * 0.015625f;
  float var  = sq * 0.015625f - mean * mean;
  float rstd = rsqrtf(var + 1e-5f);
  float* orow = outp + (size_t)(r0 + l15) * 64;
#pragma unroll
  for (int mt = 0; mt < 4; ++mt) {
    int fo = mt * 16 + quad * 4;
    f4 g  = *(const f4*)(cgb + goff + fo);
    f4 be = *(const f4*)(cgb + boff + fo);
    f4 o;
    o[0] = (vals[mt * 4 + 0] - mean) * rstd * g[0] + be[0];
    o[1] = (vals[mt * 4 + 1] - mean) * rstd * g[1] + be[1];
    o[2] = (vals[mt * 4 + 2] - mean) * rstd * g[2] + be[2];
    o[3] = (vals[mt * 4 + 3] - mean) * rstd * g[3] + be[3];
    *(f4*)(orow + fo) = o;
  }
}

__global__ __launch_bounds__(256) void xattn(
    const float* __restrict__ v1, const float* __restrict__ v2,
    const u16* __restrict__ M1, const u16* __restrict__ M2,
    const float* __restrict__ cgb,
    float* __restrict__ out1, float* __restrict__ out2) {
  const int lane = threadIdx.x & 63;
  const int wave = threadIdx.x >> 6;
  const int quad = lane >> 4;
  const int l15  = lane & 15;
  // Hoist weight A-fragments: A[m = mt*16 + l15][k = ks*32 + quad*8 + j]
  v8s a1[4][2], a2[4][2];
#pragma unroll
  for (int mt = 0; mt < 4; ++mt) {
#pragma unroll
    for (int ks = 0; ks < 2; ++ks) {
      int off = (mt * 16 + l15) * 64 + ks * 32 + quad * 8;
      a1[mt][ks] = *(const v8s*)(M1 + off);
      a2[mt][ks] = *(const v8s*)(M2 + off);
    }
  }
  const int gw = blockIdx.x * 4 + wave;   // 0..4095
#pragma unroll 1
  for (int it = 0; it < 4; ++it) {
    const int r0 = (gw + it * 4096) * 16; // 16-row tile base
    do_path(v2, v1, a1, cgb, 0,  128, 192, out1, r0, lane);  // path 1
    do_path(v1, v2, a2, cgb, 64, 256, 320, out2, r0, lane);  // path 2
  }
}

extern "C" void kernel_launch(void* const* d_in, const int* in_sizes, int n_in,
                              void* d_out, int out_size, void* d_ws, size_t ws_size,
                              hipStream_t stream) {
  const float* v1  = (const float*)d_in[0];
  const float* v2  = (const float*)d_in[1];
  const float* Wv2 = (const float*)d_in[6];
  const float* bv2 = (const float*)d_in[7];
  const float* Wo1 = (const float*)d_in[8];
  const float* bo1 = (const float*)d_in[9];
  const float* Wv1 = (const float*)d_in[14];
  const float* bv1 = (const float*)d_in[15];
  const float* Wo2 = (const float*)d_in[16];
  const float* bo2 = (const float*)d_in[17];
  const float* g1  = (const float*)d_in[18];
  const float* be1 = (const float*)d_in[19];
  const float* g2  = (const float*)d_in[20];
  const float* be2 = (const float*)d_in[21];

  u16* M1 = (u16*)d_ws;                         // 4096 bf16
  u16* M2 = M1 + 4096;                          // 4096 bf16
  float* cgb = (float*)((char*)d_ws + 16384);   // 384 f32: c1,c2,g1,be1,g2,be2

  float* out1 = (float*)d_out;
  float* out2 = out1 + (size_t)NROWS * 64;

  fuse_weights<<<8, 256, 0, stream>>>(Wo1, Wv2, bv2, bo1, Wo2, Wv1, bv1, bo2,
                                      g1, be1, g2, be2, M1, M2, cgb);
  xattn<<<1024, 256, 0, stream>>>(v1, v2, M1, M2, cgb, out1, out2);
}

// Round 3
// 301.528 us; speedup vs baseline: 1.0079x; 1.0079x over previous
//
#include <hip/hip_runtime.h>

typedef unsigned short u16;
typedef short v8s __attribute__((ext_vector_type(8)));   // 8 bf16 in 4 VGPRs
typedef float f4 __attribute__((ext_vector_type(4)));

#define NROWS 262144
// 16384 tiles of 16 rows; work unit = (tile, path); 32768 units total.

__device__ __forceinline__ u16 f2bf(float f) {
  union { float f; unsigned int i; } x; x.f = f;
  unsigned int r = x.i + 0x7fffu + ((x.i >> 16) & 1u);   // round-nearest-even
  return (u16)(r >> 16);
}

// ---------------------------------------------------------------------------
// Kernel 1: fold M = Wo @ Wv (f32 math -> bf16), c = Wo @ bv + bo (f32),
// copy g/be (f32) into ws. grid 8 x 256 -> 2048 items = mat(2) x n(64) x kg(16)
// ---------------------------------------------------------------------------
__global__ void fuse_weights(const float* __restrict__ Wo1, const float* __restrict__ Wv2,
                             const float* __restrict__ bv2, const float* __restrict__ bo1,
                             const float* __restrict__ Wo2, const float* __restrict__ Wv1,
                             const float* __restrict__ bv1, const float* __restrict__ bo2,
                             const float* __restrict__ g1,  const float* __restrict__ be1,
                             const float* __restrict__ g2,  const float* __restrict__ be2,
                             u16* __restrict__ M1, u16* __restrict__ M2,
                             float* __restrict__ cgb) {
  int item = blockIdx.x * 256 + threadIdx.x;   // 0..2047
  int mat = item >> 10;                        // 0: path1, 1: path2
  int n   = (item >> 4) & 63;                  // output feature (row of M)
  int k0  = (item & 15) * 4;                   // 4 columns per thread
  const float* Wo = mat ? Wo2 : Wo1;
  const float* Wv = mat ? Wv1 : Wv2;
  float a0 = 0.f, a1 = 0.f, a2 = 0.f, a3 = 0.f;
  for (int j = 0; j < 64; ++j) {
    float w = Wo[n * 64 + j];
    f4 wv = *(const f4*)(Wv + j * 64 + k0);
    a0 += w * wv[0];
    a1 += w * wv[1];
    a2 += w * wv[2];
    a3 += w * wv[3];
  }
  u16* M = mat ? M2 : M1;
  M[n * 64 + k0 + 0] = f2bf(a0);
  M[n * 64 + k0 + 1] = f2bf(a1);
  M[n * 64 + k0 + 2] = f2bf(a2);
  M[n * 64 + k0 + 3] = f2bf(a3);
  if ((item & 15) == 0) {
    const float* bv = mat ? bv1 : bv2;
    const float* bo = mat ? bo2 : bo1;
    float s = bo[n];
    for (int j = 0; j < 64; ++j) s += Wo[n * 64 + j] * bv[j];
    cgb[mat * 64 + n] = s;                       // c1 @0, c2 @64
    const float* g  = mat ? g2 : g1;
    const float* be = mat ? be2 : be1;
    cgb[128 + mat * 128 + n] = g[n];             // g1 @128, g2 @256
    cgb[192 + mat * 128 + n] = be[n];            // be1 @192, be2 @320
  }
}

// ---------------------------------------------------------------------------
// Kernel 2: one wave = one (16-row tile, path). D = M(64x64) @ X^T(64x16) via
// mfma_f32_16x16x32_bf16 (4 M-tiles x 2 K-steps), then +c +residual, LN, store.
// C-layout: lane holds features {mt*16 + quad*4 + reg} of batch row (lane&15).
// Waves 0..3 of a block: (tile0,p0),(tile0,p1),(tile1,p0),(tile1,p1) -> L1 reuse.
// ---------------------------------------------------------------------------
__global__ __launch_bounds__(256, 4) void xattn(
    const float* __restrict__ v1, const float* __restrict__ v2,
    const u16* __restrict__ M1, const u16* __restrict__ M2,
    const float* __restrict__ cgb,
    float* __restrict__ out1, float* __restrict__ out2) {
  const int lane = threadIdx.x & 63;
  const int wave = threadIdx.x >> 6;
  const int quad = lane >> 4;
  const int l15  = lane & 15;
  const int path = wave & 1;

  const u16*   M    = path ? M2  : M1;
  const float* xsrc = path ? v1  : v2;   // matmul input
  const float* rsrc = path ? v2  : v1;   // residual
  float*       outp = path ? (float*)0 : (float*)0; // set below (avoid select on out)
  outp = path ? out2 : out1;
  const int coff = path * 64;
  const int goff = 128 + path * 128;
  const int boff = 192 + path * 128;

  // Weight A-fragments for THIS path only: A[m = mt*16+l15][k = ks*32+quad*8+j]
  v8s a[4][2];
#pragma unroll
  for (int mt = 0; mt < 4; ++mt)
#pragma unroll
    for (int ks = 0; ks < 2; ++ks)
      a[mt][ks] = *(const v8s*)(M + (mt * 16 + l15) * 64 + ks * 32 + quad * 8);

  const int unit0 = blockIdx.x * 2 + (wave >> 1);   // 0..8191
#pragma unroll
  for (int it = 0; it < 2; ++it) {
    const int r0 = (unit0 + it * 8192) * 16;        // tile base row

    // ---- issue all 8 independent 16B loads up front ----
    const float* xrow = xsrc + (size_t)(r0 + l15) * 64 + quad * 8;
    f4 x0 = *(const f4*)(xrow);
    f4 x1 = *(const f4*)(xrow + 4);
    f4 x2 = *(const f4*)(xrow + 32);
    f4 x3 = *(const f4*)(xrow + 36);
    const float* rrow = rsrc + (size_t)(r0 + l15) * 64 + quad * 4;
    f4 rv0 = *(const f4*)(rrow);
    f4 rv1 = *(const f4*)(rrow + 16);
    f4 rv2 = *(const f4*)(rrow + 32);
    f4 rv3 = *(const f4*)(rrow + 48);

    // ---- convert B-fragment to bf16: B[k=quad*8+j][n=l15] = X[r0+l15][k] ----
    v8s b0, b1;
#pragma unroll
    for (int j = 0; j < 4; ++j) {
      b0[j]     = (short)f2bf(x0[j]);
      b0[j + 4] = (short)f2bf(x1[j]);
      b1[j]     = (short)f2bf(x2[j]);
      b1[j + 4] = (short)f2bf(x3[j]);
    }

    f4 acc[4];
#pragma unroll
    for (int mt = 0; mt < 4; ++mt) {
      f4 c = {0.f, 0.f, 0.f, 0.f};
      c = __builtin_amdgcn_mfma_f32_16x16x32_bf16(a[mt][0], b0, c, 0, 0, 0);
      c = __builtin_amdgcn_mfma_f32_16x16x32_bf16(a[mt][1], b1, c, 0, 0, 0);
      acc[mt] = c;
    }

    // ---- +bias +residual, LN stats ----
    float vals[16];
    float sum = 0.f, sq = 0.f;
    f4 rv[4] = {rv0, rv1, rv2, rv3};
#pragma unroll
    for (int mt = 0; mt < 4; ++mt) {
      int fo = mt * 16 + quad * 4;
      f4 cf = *(const f4*)(cgb + coff + fo);
#pragma unroll
      for (int j = 0; j < 4; ++j) {
        float x = acc[mt][j] + cf[j] + rv[mt][j];
        vals[mt * 4 + j] = x;
        sum += x;
        sq  += x * x;
      }
    }
    // batch row split across lanes {l, l^16, l^32, l^48}: butterfly over quads
    sum += __shfl_xor(sum, 16, 64);
    sq  += __shfl_xor(sq,  16, 64);
    sum += __shfl_xor(sum, 32, 64);
    sq  += __shfl_xor(sq,  32, 64);
    float mean = sum * 0.015625f;
    float var  = sq * 0.015625f - mean * mean;
    float rstd = rsqrtf(var + 1e-5f);

    float* orow = outp + (size_t)(r0 + l15) * 64 + quad * 4;
#pragma unroll
    for (int mt = 0; mt < 4; ++mt) {
      int fo = mt * 16 + quad * 4;
      f4 g  = *(const f4*)(cgb + goff + fo);
      f4 be = *(const f4*)(cgb + boff + fo);
      f4 o;
#pragma unroll
      for (int j = 0; j < 4; ++j)
        o[j] = (vals[mt * 4 + j] - mean) * rstd * g[j] + be[j];
      __builtin_nontemporal_store(o, (f4*)(orow + mt * 16));
    }
  }
}

extern "C" void kernel_launch(void* const* d_in, const int* in_sizes, int n_in,
                              void* d_out, int out_size, void* d_ws, size_t ws_size,
                              hipStream_t stream) {
  const float* v1  = (const float*)d_in[0];
  const float* v2  = (const float*)d_in[1];
  const float* Wv2 = (const float*)d_in[6];
  const float* bv2 = (const float*)d_in[7];
  const float* Wo1 = (const float*)d_in[8];
  const float* bo1 = (const float*)d_in[9];
  const float* Wv1 = (const float*)d_in[14];
  const float* bv1 = (const float*)d_in[15];
  const float* Wo2 = (const float*)d_in[16];
  const float* bo2 = (const float*)d_in[17];
  const float* g1  = (const float*)d_in[18];
  const float* be1 = (const float*)d_in[19];
  const float* g2  = (const float*)d_in[20];
  const float* be2 = (const float*)d_in[21];

  u16* M1 = (u16*)d_ws;                         // 4096 bf16
  u16* M2 = M1 + 4096;                          // 4096 bf16
  float* cgb = (float*)((char*)d_ws + 16384);   // 384 f32: c1,c2,g1,be1,g2,be2

  float* out1 = (float*)d_out;
  float* out2 = out1 + (size_t)NROWS * 64;

  fuse_weights<<<8, 256, 0, stream>>>(Wo1, Wv2, bv2, bo1, Wo2, Wv1, bv1, bo2,
                                      g1, be1, g2, be2, M1, M2, cgb);
  xattn<<<4096, 256, 0, stream>>>(v1, v2, M1, M2, cgb, out1, out2);
}